// Round 2
// baseline (7265.978 us; speedup 1.0000x reference)
//
#include <hip/hip_runtime.h>
#include <hip/hip_bf16.h>
#include <stdint.h>

// ContextEncoder: 2-layer LSTM x2 sides, B=256 T=128 D=300 H=512, gather-last, @[1024,200].
// Time-chunked pipeline (TC=16, 8 chunks) to keep ws usage ~67 MB:
//   per chunk: pad_x -> gemm(Zpre=x@Wx+b, MFMA-frag layout) -> lstm_rec (persistent
//   256-block, W_h in VGPRs, cross-block h exchange via agent-scope atomics)
//   for layer 0, then same for layer 1. h lives in small rings (16 / 2 slots);
//   c-state persists across chunk launches in fp32.

using short4_t = __attribute__((ext_vector_type(4))) short;
using short8_t = __attribute__((ext_vector_type(8))) short;
using f32x4    = __attribute__((ext_vector_type(4))) float;

#define B_   256
#define T_   128
#define Draw 300
#define Dp   320
#define H_   512
#define G4   2048
#define TC   16          // time-chunk length
#define MC   (TC * 256)  // rows per chunk (4096)

__device__ __forceinline__ short f2bf(float x){
  union { float f; unsigned u; } v; v.f = x;
  unsigned r = (v.u + 0x7FFFu + ((v.u >> 16) & 1u)) >> 16;
  return (short)r;
}
__device__ __forceinline__ float bf2f(short b){
  union { unsigned u; float f; } v; v.u = ((unsigned)(unsigned short)b) << 16;
  return v.f;
}
__device__ __forceinline__ float sigf(float x){ return 1.f / (1.f + __expf(-x)); }
__device__ __forceinline__ float tanh_f(float x){
  x = fmaxf(-15.f, fminf(15.f, x));
  float e = __expf(-2.f * x);
  return (1.f - e) / (1.f + e);
}
__device__ __forceinline__ void gload_lds16(const void* g, void* l){
  __builtin_amdgcn_global_load_lds((const __attribute__((address_space(1))) void*)g,
                                   (__attribute__((address_space(3))) void*)l, 16, 0, 0);
}

// ---------- prep: pad/cast/transpose one time-chunk of X into [2][tl*256+b][320] ----------
__global__ __launch_bounds__(256) void pad_x_chunk(const float* __restrict__ xl,
                                                   const float* __restrict__ xr,
                                                   short* __restrict__ xpadc, int t0)
{
  const int N = 2 * MC * Dp;
  for(int i = blockIdx.x * 256 + threadIdx.x; i < N; i += gridDim.x * 256){
    int side = i / (MC * Dp);
    int rem  = i - side * (MC * Dp);
    int row  = rem / Dp;
    int d    = rem - row * Dp;
    int tl = row >> 8, b = row & 255;
    const float* x = side ? xr : xl;
    float v = (d < Draw) ? x[((size_t)b * T_ + (t0 + tl)) * Draw + d] : 0.f;
    xpadc[i] = f2bf(v);
  }
}

// ---------- prep: W[k][n] (f32) -> WT[n][k] (bf16), zero-pad k>=krows ----------
__global__ __launch_bounds__(256) void transpose_w(const float* __restrict__ in,
                                                   short* __restrict__ out,
                                                   int row_off, int krows, int K)
{
  __shared__ float tile[32][33];
  int k0 = blockIdx.x * 32, n0 = blockIdx.y * 32;
  int tx = threadIdx.x & 31, ty = threadIdx.x >> 5;   // ty 0..7
  #pragma unroll
  for(int p = 0; p < 4; p++){
    int k = k0 + ty + p * 8;
    float v = (k < krows) ? in[(size_t)(k + row_off) * G4 + (n0 + tx)] : 0.f;
    tile[ty + p * 8][tx] = v;
  }
  __syncthreads();
  #pragma unroll
  for(int p = 0; p < 4; p++){
    int n = n0 + ty + p * 8;
    out[(size_t)n * K + k0 + tx] = f2bf(tile[tx][ty + p * 8]);
  }
}

// ---------- chunk GEMM: Z[m][n] = A[m][:K] @ W^T[n][:K] + bias[n], both sides ----------
// M = 4096 (one chunk). Output in MFMA-C-fragment tiled layout: tile (gm=m>>4, gn=n>>4),
// lane l holds rows (l>>4)*4+r, col l&15, stored as short4 at Z[((gm*128+gn)*64+l)*4].
__global__ __launch_bounds__(256, 2) void gemm_zpre(
    const short* __restrict__ Al, const short* __restrict__ Ar,
    const short* __restrict__ Wl, const short* __restrict__ Wr,
    const float* __restrict__ bl, const float* __restrict__ br,
    short* __restrict__ Zl, short* __restrict__ Zr, int K)
{
  __shared__ short As[8192];
  __shared__ short Bs[8192];
  const int side = blockIdx.z;
  const short* A = side ? Ar : Al;
  const short* W = side ? Wr : Wl;
  const float* bias = side ? br : bl;
  short* Zo = side ? Zr : Zl;
  const int m0 = blockIdx.x * 128, n0 = blockIdx.y * 128;
  const int tid = threadIdx.x, l = tid & 63, w = tid >> 6;
  const int wm = w & 1, wn = w >> 1;
  const int ln = l & 15, lq = l >> 4;

  f32x4 acc[4][4];
  const f32x4 z4 = {0.f, 0.f, 0.f, 0.f};
  #pragma unroll
  for(int i = 0; i < 4; i++)
    #pragma unroll
    for(int j = 0; j < 4; j++) acc[i][j] = z4;

  for(int k0 = 0; k0 < K; k0 += 64){
    __syncthreads();
    #pragma unroll
    for(int i = 0; i < 4; i++){
      int qb = w * 256 + i * 64;          // wave-uniform LDS chunk base
      int q  = qb + l;
      int row = q >> 3, c = q & 7, cs = c ^ (row & 7);   // XOR swizzle
      gload_lds16(A + (size_t)(m0 + row) * K + k0 + cs * 8, As + qb * 8);
      gload_lds16(W + (size_t)(n0 + row) * K + k0 + cs * 8, Bs + qb * 8);
    }
    __syncthreads();
    #pragma unroll
    for(int kt = 0; kt < 2; kt++){
      short8_t af[4], bf[4];
      #pragma unroll
      for(int i = 0; i < 4; i++){
        int mr = wm * 64 + i * 16 + ln;
        int nr = wn * 64 + i * 16 + ln;
        int cw = kt * 4 + lq;
        af[i] = *(const short8_t*)(As + (mr * 8 + (cw ^ (mr & 7))) * 8);
        bf[i] = *(const short8_t*)(Bs + (nr * 8 + (cw ^ (nr & 7))) * 8);
      }
      #pragma unroll
      for(int i = 0; i < 4; i++)
        #pragma unroll
        for(int j = 0; j < 4; j++)
          acc[i][j] = __builtin_amdgcn_mfma_f32_16x16x32_bf16(af[i], bf[j], acc[i][j], 0, 0, 0);
    }
  }
  #pragma unroll
  for(int j = 0; j < 4; j++){
    int n = n0 + wn * 64 + j * 16 + ln;
    float bv = bias[n];
    int gn = (n0 >> 4) + wn * 4 + j;
    #pragma unroll
    for(int i = 0; i < 4; i++){
      int gm = (m0 >> 4) + wm * 4 + i;
      short4_t sv;
      #pragma unroll
      for(int r = 0; r < 4; r++) sv[r] = f2bf(acc[i][j][r] + bv);
      *(short4_t*)(Zo + ((size_t)(gm * 128 + gn) * 64 + l) * 4) = sv;
    }
  }
}

// ---------- recurrent chunk kernel: TC steps of one LSTM layer, both sides ----------
// 256 blocks: side(2) x group(16, 16 batch rows) x colblk(8, 64 h-cols).
// Wave w of 4 owns 16 h-cols; W_h fragments (4 gates x 16 k-tiles) live in VGPRs.
// h exchange through ring buffer (slot = t & slot_mask), agent-scope atomics +
// per-(layer,side,group) release counters (cumulative across chunk launches).
__global__ __launch_bounds__(256, 1) void lstm_rec(
    const short* __restrict__ Zl, const short* __restrict__ Zr,
    const short* __restrict__ Wtl, const short* __restrict__ Wtr,
    short* __restrict__ hl, short* __restrict__ hr,
    float* __restrict__ cstate,
    const int* lenl, const int* lenr, float* ctx,
    unsigned* flags, int layer, int t0, int slot_mask)
{
  const int blk = blockIdx.x;
  const int side = blk >> 7;
  const int g = (blk >> 3) & 15;
  const int cb = blk & 7;
  const int tid = threadIdx.x, l = tid & 63, w = tid >> 6;
  const int ln = l & 15, lq = l >> 4;
  const short* Z  = side ? Zr : Zl;
  const short* Wt = side ? Wtr : Wtl;        // WhT: [2048 n][512 k] bf16
  short* hseq = side ? hr : hl;              // ring: [slots][256][512] bf16
  const int* len = side ? lenr : lenl;
  unsigned* flag = flags + ((layer * 2 + side) * 16 + g);
  const int hc = cb * 64 + w * 16;           // this wave's h-col base
  const int rbase = g * 16;

  // Preload W_h B-fragments (loop-invariant): lane holds B[k][n], n = col + ln.
  short8_t Bf[4][16];
  #pragma unroll
  for(int gate = 0; gate < 4; gate++){
    const short* wp = Wt + (size_t)(gate * 512 + hc + ln) * 512 + lq * 8;
    #pragma unroll
    for(int kt = 0; kt < 16; kt++)
      Bf[gate][kt] = *(const short8_t*)(wp + kt * 32);
  }

  // c-state: rows rbase + lq*4+r, col hc+ln
  float* cptr = cstate + ((size_t)((layer * 2 + side) * 256 + rbase + lq * 4) * 512) + hc + ln;
  float cst[4];
  if(t0 == 0){
    #pragma unroll
    for(int r = 0; r < 4; r++) cst[r] = 0.f;
  } else {
    #pragma unroll
    for(int r = 0; r < 4; r++) cst[r] = cptr[(size_t)r * 512];
  }

  for(int tl = 0; tl < TC; tl++){
    const int t = t0 + tl;
    // acc init from Zpre (issued before the spin so latency overlaps the wait)
    f32x4 acc[4];
    {
      const int gm = tl * 16 + g;
      #pragma unroll
      for(int gate = 0; gate < 4; gate++){
        int gn = gate * 32 + cb * 4 + w;
        short4_t zv = *(const short4_t*)(Z + ((size_t)(gm * 128 + gn) * 64 + l) * 4);
        #pragma unroll
        for(int r = 0; r < 4; r++) acc[gate][r] = bf2f(zv[r]);
      }
    }
    if(t > 0){
      const unsigned target = 8u * (unsigned)t;
      while(__hip_atomic_load(flag, __ATOMIC_RELAXED, __HIP_MEMORY_SCOPE_AGENT) < target)
        __builtin_amdgcn_s_sleep(2);
      __builtin_amdgcn_fence(__ATOMIC_ACQUIRE, "agent");
      // A-frags from ring slot (t-1): lane row = rbase+ln, k = kt*32 + lq*8 + j
      const short* ap = hseq + ((size_t)(((t - 1) & slot_mask) * 256 + rbase + ln)) * 512 + lq * 8;
      #pragma unroll
      for(int kt = 0; kt < 16; kt++){
        short8_t af = *(const short8_t*)(ap + kt * 32);
        #pragma unroll
        for(int gate = 0; gate < 4; gate++)
          acc[gate] = __builtin_amdgcn_mfma_f32_16x16x32_bf16(af, Bf[gate][kt], acc[gate], 0, 0, 0);
      }
    }
    // activations (gate order i, j, f, o; forget bias +1)
    float hv[4];
    #pragma unroll
    for(int r = 0; r < 4; r++){
      float iv = sigf(acc[0][r]);
      float jv = tanh_f(acc[1][r]);
      float fv = sigf(acc[2][r] + 1.0f);
      float ov = sigf(acc[3][r]);
      float c  = cst[r] * fv + iv * jv;
      cst[r] = c;
      hv[r] = tanh_f(c) * ov;
    }
    // publish h into ring slot t (device-scope stores for cross-XCD visibility)
    short* hout = hseq + ((size_t)((t & slot_mask) * 256 + rbase)) * 512 + hc + ln;
    #pragma unroll
    for(int r = 0; r < 4; r++)
      __hip_atomic_store(hout + (size_t)(lq * 4 + r) * 512, f2bf(hv[r]),
                         __ATOMIC_RELAXED, __HIP_MEMORY_SCOPE_AGENT);
    if(len){ // layer 1: gather last valid h into ctx (fp32)
      #pragma unroll
      for(int r = 0; r < 4; r++){
        int b = rbase + lq * 4 + r;
        if(len[b] - 1 == t)
          ctx[(size_t)b * 1024 + side * 512 + hc + ln] = hv[r];
      }
    }
    __syncthreads();   // drains all waves' stores (vmcnt 0) before the release add
    if(tid == 0)
      __hip_atomic_fetch_add(flag, 1u, __ATOMIC_RELEASE, __HIP_MEMORY_SCOPE_AGENT);
  }
  // persist c-state for next chunk
  #pragma unroll
  for(int r = 0; r < 4; r++) cptr[(size_t)r * 512] = cst[r];
}

// ---------- final: out[256][200] = ctx[256][1024] @ W[1024][200] (fp32) ----------
__global__ __launch_bounds__(256) void final_mm(const float* __restrict__ ctx,
                                                const float* __restrict__ W,
                                                float* __restrict__ out)
{
  __shared__ float cs[4][1024];
  const int tid = threadIdx.x;
  const int b0 = blockIdx.x * 4;
  for(int i = tid; i < 4 * 1024; i += 256)
    cs[i >> 10][i & 1023] = ctx[(size_t)b0 * 1024 + i];
  __syncthreads();
  if(tid < 200){
    float a0 = 0, a1 = 0, a2 = 0, a3 = 0;
    for(int k = 0; k < 1024; k++){
      float wv = W[k * 200 + tid];
      a0 += cs[0][k] * wv; a1 += cs[1][k] * wv;
      a2 += cs[2][k] * wv; a3 += cs[3][k] * wv;
    }
    out[(size_t)(b0 + 0) * 200 + tid] = a0;
    out[(size_t)(b0 + 1) * 200 + tid] = a1;
    out[(size_t)(b0 + 2) * 200 + tid] = a2;
    out[(size_t)(b0 + 3) * 200 + tid] = a3;
  }
}

extern "C" void kernel_launch(void* const* d_in, const int* in_sizes, int n_in,
                              void* d_out, int out_size, void* d_ws, size_t ws_size,
                              hipStream_t stream)
{
  (void)in_sizes; (void)n_in; (void)out_size; (void)ws_size;
  const float* xl   = (const float*)d_in[0];
  const float* xr   = (const float*)d_in[1];
  const int*   lenl = (const int*)  d_in[2];
  const int*   lenr = (const int*)  d_in[3];
  const float* lW0  = (const float*)d_in[4];
  const float* lb0  = (const float*)d_in[5];
  const float* lW1  = (const float*)d_in[6];
  const float* lb1  = (const float*)d_in[7];
  const float* rW0  = (const float*)d_in[8];
  const float* rb0  = (const float*)d_in[9];
  const float* rW1  = (const float*)d_in[10];
  const float* rb1  = (const float*)d_in[11];
  const float* tW   = (const float*)d_in[12];
  float* out = (float*)d_out;
  char* ws = (char*)d_ws;

  constexpr size_t SZ_WXT0 = (size_t)2048 * Dp * 2;       // 1.31 MB
  constexpr size_t SZ_WT   = (size_t)2048 * 512 * 2;      // 2.10 MB
  constexpr size_t SZ_XPC  = (size_t)2 * MC * Dp * 2;     // 5.24 MB
  constexpr size_t SZ_ZPRE = (size_t)MC * 2048 * 2;       // 16.8 MB per side
  constexpr size_t SZ_H0   = (size_t)TC * 256 * 512 * 2;  // 4.19 MB per side
  constexpr size_t SZ_H1   = (size_t)2 * 256 * 512 * 2;   // 0.52 MB per side
  constexpr size_t SZ_CST  = (size_t)2 * 2 * 256 * 512 * 4; // 2.10 MB
  constexpr size_t SZ_CTX  = (size_t)256 * 1024 * 4;      // 1.05 MB

  size_t off = 0;
  auto carve = [&](size_t sz){ size_t o = off; off += (sz + 255) & ~(size_t)255; return o; };
  size_t o_wxt0_l = carve(SZ_WXT0), o_wxt0_r = carve(SZ_WXT0);
  size_t o_wht0_l = carve(SZ_WT),   o_wht0_r = carve(SZ_WT);
  size_t o_wxt1_l = carve(SZ_WT),   o_wxt1_r = carve(SZ_WT);
  size_t o_wht1_l = carve(SZ_WT),   o_wht1_r = carve(SZ_WT);
  size_t o_xpc    = carve(SZ_XPC);
  size_t o_zpre_l = carve(SZ_ZPRE), o_zpre_r = carve(SZ_ZPRE);
  size_t o_h0_l   = carve(SZ_H0),   o_h0_r   = carve(SZ_H0);
  size_t o_h1_l   = carve(SZ_H1),   o_h1_r   = carve(SZ_H1);
  size_t o_cst    = carve(SZ_CST);
  size_t o_ctx    = carve(SZ_CTX);
  size_t o_flags  = carve(256);
  // total ~67 MB

  short* wxt0_l = (short*)(ws + o_wxt0_l);
  short* wxt0_r = (short*)(ws + o_wxt0_r);
  short* wht0_l = (short*)(ws + o_wht0_l);
  short* wht0_r = (short*)(ws + o_wht0_r);
  short* wxt1_l = (short*)(ws + o_wxt1_l);
  short* wxt1_r = (short*)(ws + o_wxt1_r);
  short* wht1_l = (short*)(ws + o_wht1_l);
  short* wht1_r = (short*)(ws + o_wht1_r);
  short* xpc_l  = (short*)(ws + o_xpc);
  short* xpc_r  = xpc_l + (size_t)MC * Dp;
  short* zpre_l = (short*)(ws + o_zpre_l);
  short* zpre_r = (short*)(ws + o_zpre_r);
  short* h0_l   = (short*)(ws + o_h0_l);
  short* h0_r   = (short*)(ws + o_h0_r);
  short* h1_l   = (short*)(ws + o_h1_l);
  short* h1_r   = (short*)(ws + o_h1_r);
  float* cst    = (float*)(ws + o_cst);
  float* ctx    = (float*)(ws + o_ctx);
  unsigned* flags = (unsigned*)(ws + o_flags);

  hipMemsetAsync(flags, 0, 256, stream);

  transpose_w<<<dim3(Dp / 32, 64), 256, 0, stream>>>(lW0, wxt0_l,   0, Draw, Dp);
  transpose_w<<<dim3(Dp / 32, 64), 256, 0, stream>>>(rW0, wxt0_r,   0, Draw, Dp);
  transpose_w<<<dim3(16, 64),      256, 0, stream>>>(lW0, wht0_l, 300,  512, 512);
  transpose_w<<<dim3(16, 64),      256, 0, stream>>>(rW0, wht0_r, 300,  512, 512);
  transpose_w<<<dim3(16, 64),      256, 0, stream>>>(lW1, wxt1_l,   0,  512, 512);
  transpose_w<<<dim3(16, 64),      256, 0, stream>>>(rW1, wxt1_r,   0,  512, 512);
  transpose_w<<<dim3(16, 64),      256, 0, stream>>>(lW1, wht1_l, 512,  512, 512);
  transpose_w<<<dim3(16, 64),      256, 0, stream>>>(rW1, wht1_r, 512,  512, 512);

  for(int c = 0; c < T_ / TC; c++){
    const int t0 = c * TC;
    pad_x_chunk<<<4096, 256, 0, stream>>>(xl, xr, xpc_l, t0);
    // layer 0: Zpre = xchunk @ Wx0 + b0
    gemm_zpre<<<dim3(MC / 128, 16, 2), 256, 0, stream>>>(xpc_l, xpc_r, wxt0_l, wxt0_r,
                                                         lb0, rb0, zpre_l, zpre_r, Dp);
    lstm_rec<<<256, 256, 0, stream>>>(zpre_l, zpre_r, wht0_l, wht0_r, h0_l, h0_r,
                                      cst, nullptr, nullptr, nullptr, flags, 0, t0, 15);
    // layer 1: Zpre = h0chunk @ Wx1 + b1  (ring slot == tl for this chunk)
    gemm_zpre<<<dim3(MC / 128, 16, 2), 256, 0, stream>>>(h0_l, h0_r, wxt1_l, wxt1_r,
                                                         lb1, rb1, zpre_l, zpre_r, 512);
    lstm_rec<<<256, 256, 0, stream>>>(zpre_l, zpre_r, wht1_l, wht1_r, h1_l, h1_r,
                                      cst, lenl, lenr, ctx, flags, 1, t0, 1);
  }

  final_mm<<<64, 256, 0, stream>>>(ctx, tW, out);
}

// Round 7
// 5070.063 us; speedup vs baseline: 1.4331x; 1.4331x over previous
//
#include <hip/hip_runtime.h>
#include <hip/hip_bf16.h>
#include <stdint.h>

// ContextEncoder: 2-layer LSTM x2 sides, B=256 T=128 D=300 H=512, gather-last, @[1024,200].
// Time-chunked pipeline (TC=16, 8 chunks), ws ~67 MB.
// R7: FIX the reader A-fragment stride bug introduced in R3: `ap` is ull*, the
// per-k-tile stride is 32 shorts = 64 B = 8 ULLs, but R3..R6 used ap+kt*4 (32 B).
// That read wrong/duplicated k-slices -> deterministic wrong h@Wh regardless of
// coherence -- explaining four bit-identical failures under three different
// publish primitives. Protocol otherwise unchanged from R6: publish = returning
// agent-scope atomic exchange (non-demotable RMW), read = 64-bit relaxed agent
// atomic loads, release = s_waitcnt vmcnt(0) + __syncthreads + relaxed per-block
// flag add (target 8*t). No wbl2/buffer_inv anywhere in the loop.

using short4_t = __attribute__((ext_vector_type(4))) short;
using short8_t = __attribute__((ext_vector_type(8))) short;
using f32x4    = __attribute__((ext_vector_type(4))) float;

#define B_   256
#define T_   128
#define Draw 300
#define Dp   320
#define H_   512
#define G4   2048
#define TC   16          // time-chunk length
#define MC   (TC * 256)  // rows per chunk (4096)

__device__ __forceinline__ short f2bf(float x){
  union { float f; unsigned u; } v; v.f = x;
  unsigned r = (v.u + 0x7FFFu + ((v.u >> 16) & 1u)) >> 16;
  return (short)r;
}
__device__ __forceinline__ float bf2f(short b){
  union { unsigned u; float f; } v; v.u = ((unsigned)(unsigned short)b) << 16;
  return v.f;
}
__device__ __forceinline__ float sigf(float x){ return 1.f / (1.f + __expf(-x)); }
__device__ __forceinline__ float tanh_f(float x){
  x = fmaxf(-15.f, fminf(15.f, x));
  float e = __expf(-2.f * x);
  return (1.f - e) / (1.f + e);
}
__device__ __forceinline__ void gload_lds16(const void* g, void* l){
  __builtin_amdgcn_global_load_lds((const __attribute__((address_space(1))) void*)g,
                                   (__attribute__((address_space(3))) void*)l, 16, 0, 0);
}

// ---------- prep: pad/cast/transpose one time-chunk of X into [2][tl*256+b][320] ----------
__global__ __launch_bounds__(256) void pad_x_chunk(const float* __restrict__ xl,
                                                   const float* __restrict__ xr,
                                                   short* __restrict__ xpadc, int t0)
{
  const int N = 2 * MC * Dp;
  for(int i = blockIdx.x * 256 + threadIdx.x; i < N; i += gridDim.x * 256){
    int side = i / (MC * Dp);
    int rem  = i - side * (MC * Dp);
    int row  = rem / Dp;
    int d    = rem - row * Dp;
    int tl = row >> 8, b = row & 255;
    const float* x = side ? xr : xl;
    float v = (d < Draw) ? x[((size_t)b * T_ + (t0 + tl)) * Draw + d] : 0.f;
    xpadc[i] = f2bf(v);
  }
}

// ---------- prep: W[k][n] (f32) -> WT[n][k] (bf16), zero-pad k>=krows ----------
__global__ __launch_bounds__(256) void transpose_w(const float* __restrict__ in,
                                                   short* __restrict__ out,
                                                   int row_off, int krows, int K)
{
  __shared__ float tile[32][33];
  int k0 = blockIdx.x * 32, n0 = blockIdx.y * 32;
  int tx = threadIdx.x & 31, ty = threadIdx.x >> 5;   // ty 0..7
  #pragma unroll
  for(int p = 0; p < 4; p++){
    int k = k0 + ty + p * 8;
    float v = (k < krows) ? in[(size_t)(k + row_off) * G4 + (n0 + tx)] : 0.f;
    tile[ty + p * 8][tx] = v;
  }
  __syncthreads();
  #pragma unroll
  for(int p = 0; p < 4; p++){
    int n = n0 + ty + p * 8;
    out[(size_t)n * K + k0 + tx] = f2bf(tile[tx][ty + p * 8]);
  }
}

// ---------- chunk GEMM: Z[m][n] = A[m][:K] @ W^T[n][:K] + bias[n], both sides ----------
// M = 4096 (one chunk). Output in MFMA-C-fragment tiled layout: tile (gm=m>>4, gn=n>>4),
// lane l holds rows (l>>4)*4+r, col l&15, stored as short4 at Z[((gm*128+gn)*64+l)*4].
__global__ __launch_bounds__(256, 2) void gemm_zpre(
    const short* __restrict__ Al, const short* __restrict__ Ar,
    const short* __restrict__ Wl, const short* __restrict__ Wr,
    const float* __restrict__ bl, const float* __restrict__ br,
    short* __restrict__ Zl, short* __restrict__ Zr, int K)
{
  __shared__ short As[8192];
  __shared__ short Bs[8192];
  const int side = blockIdx.z;
  const short* A = side ? Ar : Al;
  const short* W = side ? Wr : Wl;
  const float* bias = side ? br : bl;
  short* Zo = side ? Zr : Zl;
  const int m0 = blockIdx.x * 128, n0 = blockIdx.y * 128;
  const int tid = threadIdx.x, l = tid & 63, w = tid >> 6;
  const int wm = w & 1, wn = w >> 1;
  const int ln = l & 15, lq = l >> 4;

  f32x4 acc[4][4];
  const f32x4 z4 = {0.f, 0.f, 0.f, 0.f};
  #pragma unroll
  for(int i = 0; i < 4; i++)
    #pragma unroll
    for(int j = 0; j < 4; j++) acc[i][j] = z4;

  for(int k0 = 0; k0 < K; k0 += 64){
    __syncthreads();
    #pragma unroll
    for(int i = 0; i < 4; i++){
      int qb = w * 256 + i * 64;          // wave-uniform LDS chunk base
      int q  = qb + l;
      int row = q >> 3, c = q & 7, cs = c ^ (row & 7);   // XOR swizzle
      gload_lds16(A + (size_t)(m0 + row) * K + k0 + cs * 8, As + qb * 8);
      gload_lds16(W + (size_t)(n0 + row) * K + k0 + cs * 8, Bs + qb * 8);
    }
    __syncthreads();
    #pragma unroll
    for(int kt = 0; kt < 2; kt++){
      short8_t af[4], bf[4];
      #pragma unroll
      for(int i = 0; i < 4; i++){
        int mr = wm * 64 + i * 16 + ln;
        int nr = wn * 64 + i * 16 + ln;
        int cw = kt * 4 + lq;
        af[i] = *(const short8_t*)(As + (mr * 8 + (cw ^ (mr & 7))) * 8);
        bf[i] = *(const short8_t*)(Bs + (nr * 8 + (cw ^ (nr & 7))) * 8);
      }
      #pragma unroll
      for(int i = 0; i < 4; i++)
        #pragma unroll
        for(int j = 0; j < 4; j++)
          acc[i][j] = __builtin_amdgcn_mfma_f32_16x16x32_bf16(af[i], bf[j], acc[i][j], 0, 0, 0);
    }
  }
  #pragma unroll
  for(int j = 0; j < 4; j++){
    int n = n0 + wn * 64 + j * 16 + ln;
    float bv = bias[n];
    int gn = (n0 >> 4) + wn * 4 + j;
    #pragma unroll
    for(int i = 0; i < 4; i++){
      int gm = (m0 >> 4) + wm * 4 + i;
      short4_t sv;
      #pragma unroll
      for(int r = 0; r < 4; r++) sv[r] = f2bf(acc[i][j][r] + bv);
      *(short4_t*)(Zo + ((size_t)(gm * 128 + gn) * 64 + l) * 4) = sv;
    }
  }
}

// ---------- recurrent chunk kernel: TC steps of one LSTM layer, both sides ----------
// 256 blocks: side(2) x group(16, 16 batch rows) x colblk(8, 64 h-cols).
// Wave w of 4 owns 16 h-cols; W_h fragments (4 gates x 16 k-tiles) live in VGPRs.
// h exchange through ring buffer (slot = t & slot_mask): publish = RETURNING
// agent-scope atomic exchange, read = 64-bit relaxed agent atomic loads.
// Release = s_waitcnt vmcnt(0) + __syncthreads + relaxed per-block flag add
// (target 8*t). A-fragment k-tile stride = 32 shorts = 8 ULLs (R7 fix).
__global__ __launch_bounds__(256, 1) void lstm_rec(
    const short* __restrict__ Zl, const short* __restrict__ Zr,
    const short* __restrict__ Wtl, const short* __restrict__ Wtr,
    short* __restrict__ hl, short* __restrict__ hr,
    float* __restrict__ cstate,
    const int* lenl, const int* lenr, float* ctx,
    unsigned* flags, int layer, int t0, int slot_mask)
{
  const int blk = blockIdx.x;
  const int side = blk >> 7;
  const int g = (blk >> 3) & 15;
  const int cb = blk & 7;
  const int tid = threadIdx.x, l = tid & 63, w = tid >> 6;
  const int ln = l & 15, lq = l >> 4;
  const short* Z  = side ? Zr : Zl;
  const short* Wt = side ? Wtr : Wtl;        // WhT: [2048 n][512 k] bf16
  short* hseq = side ? hr : hl;              // ring: [slots][256][512] bf16
  const int* len = side ? lenr : lenl;
  unsigned* flag = flags + ((layer * 2 + side) * 16 + g);
  const int hc = cb * 64 + w * 16;           // this wave's h-col base
  const int rbase = g * 16;

  // Preload W_h B-fragments (loop-invariant): lane holds B[k][n], n = col + ln.
  short8_t Bf[4][16];
  #pragma unroll
  for(int gate = 0; gate < 4; gate++){
    const short* wp = Wt + (size_t)(gate * 512 + hc + ln) * 512 + lq * 8;
    #pragma unroll
    for(int kt = 0; kt < 16; kt++)
      Bf[gate][kt] = *(const short8_t*)(wp + kt * 32);
  }

  // c-state: rows rbase + lq*4+r, col hc+ln
  float* cptr = cstate + ((size_t)((layer * 2 + side) * 256 + rbase + lq * 4) * 512) + hc + ln;
  float cst[4];
  if(t0 == 0){
    #pragma unroll
    for(int r = 0; r < 4; r++) cst[r] = 0.f;
  } else {
    #pragma unroll
    for(int r = 0; r < 4; r++) cst[r] = cptr[(size_t)r * 512];
  }

  unsigned junk = 0;   // consumes exchange results so the RMW can't be demoted

  for(int tl = 0; tl < TC; tl++){
    const int t = t0 + tl;
    // Z prefetch (plain cached loads, issued before the spin)
    short4_t zv[4];
    {
      const int gm = tl * 16 + g;
      #pragma unroll
      for(int gate = 0; gate < 4; gate++){
        int gn = gate * 32 + cb * 4 + w;
        zv[gate] = *(const short4_t*)(Z + ((size_t)(gm * 128 + gn) * 64 + l) * 4);
      }
    }
    short8_t af[16];
    if(t > 0){
      const unsigned target = 8u * (unsigned)t;
      while(__hip_atomic_load(flag, __ATOMIC_RELAXED, __HIP_MEMORY_SCOPE_AGENT) < target)
        __builtin_amdgcn_s_sleep(1);
      __atomic_signal_fence(__ATOMIC_ACQUIRE);
      // A-frags from ring slot (t-1): lane row = rbase+ln, k = kt*32 + lq*8 + j.
      // ap is ULL*: row base + lq*8 shorts; k-tile stride = 32 shorts = 8 ULLs.
      const unsigned long long* ap = (const unsigned long long*)
          (hseq + ((size_t)(((t - 1) & slot_mask) * 256 + rbase + ln)) * 512 + lq * 8);
      #pragma unroll
      for(int kt = 0; kt < 16; kt++){
        union { unsigned long long u[2]; short8_t v; } tmp;
        tmp.u[0] = __hip_atomic_load(ap + kt * 8,     __ATOMIC_RELAXED, __HIP_MEMORY_SCOPE_AGENT);
        tmp.u[1] = __hip_atomic_load(ap + kt * 8 + 1, __ATOMIC_RELAXED, __HIP_MEMORY_SCOPE_AGENT);
        af[kt] = tmp.v;
      }
    }
    f32x4 acc[4];
    #pragma unroll
    for(int gate = 0; gate < 4; gate++)
      #pragma unroll
      for(int r = 0; r < 4; r++) acc[gate][r] = bf2f(zv[gate][r]);
    if(t > 0){
      #pragma unroll
      for(int kt = 0; kt < 16; kt++)
        #pragma unroll
        for(int gate = 0; gate < 4; gate++)
          acc[gate] = __builtin_amdgcn_mfma_f32_16x16x32_bf16(af[kt], Bf[gate][kt], acc[gate], 0, 0, 0);
    }
    // activations (gate order i, j, f, o; forget bias +1)
    float hv[4];
    #pragma unroll
    for(int r = 0; r < 4; r++){
      float iv = sigf(acc[0][r]);
      float jv = tanh_f(acc[1][r]);
      float fv = sigf(acc[2][r] + 1.0f);
      float ov = sigf(acc[3][r]);
      float c  = cst[r] * fv + iv * jv;
      cst[r] = c;
      hv[r] = tanh_f(c) * ov;
    }
    // publish h into ring slot t: lane pairs pack 2 bf16 cols into a dword; even
    // lanes issue a RETURNING agent-scope atomic exchange (true RMW; result is
    // consumed below so it cannot be demoted to a store).
    {
      short* hrow = hseq + ((size_t)((t & slot_mask) * 256 + rbase + lq * 4)) * 512 + hc + ln;
      #pragma unroll
      for(int r = 0; r < 4; r++){
        float pv = __shfl_xor(hv[r], 1, 64);      // partner col's value
        unsigned lo = (unsigned short)f2bf(hv[r]);
        unsigned hi = (unsigned short)f2bf(pv);
        if((ln & 1) == 0){
          unsigned* addr = (unsigned*)(hrow + (size_t)r * 512);
          junk ^= __hip_atomic_exchange(addr, lo | (hi << 16),
                                        __ATOMIC_RELAXED, __HIP_MEMORY_SCOPE_AGENT);
        }
      }
    }
    if(len){ // layer 1: gather last valid h into ctx (fp32; read next dispatch)
      #pragma unroll
      for(int r = 0; r < 4; r++){
        int b = rbase + lq * 4 + r;
        if(len[b] - 1 == t)
          ctx[(size_t)b * 1024 + side * 512 + hc + ln] = hv[r];
      }
    }
    // release: drain the exchanges, sync block, one relaxed flag add (RMW).
    __atomic_signal_fence(__ATOMIC_SEQ_CST);
    asm volatile("s_waitcnt vmcnt(0)" ::: "memory");
    __syncthreads();
    if(tid == 0)
      __hip_atomic_fetch_add(flag, 1u, __ATOMIC_RELAXED, __HIP_MEMORY_SCOPE_AGENT);
  }
  // persist c-state for next chunk (plain stores; next dispatch sees them via
  // the AQL kernel-end release)
  #pragma unroll
  for(int r = 0; r < 4; r++) cptr[(size_t)r * 512] = cst[r];

  // opaque sink: t0 <= 112 always, so this never fires; keeps `junk` (and thus
  // every exchange's result) live. flags[64..] is a reserved scratch slot.
  if(junk == 0xDEADBEEFu && t0 > 10000)
    __hip_atomic_fetch_add(flags + 64 + (layer * 2 + side), junk,
                           __ATOMIC_RELAXED, __HIP_MEMORY_SCOPE_AGENT);
}

// ---------- final: out[256][200] = ctx[256][1024] @ W[1024][200] (fp32) ----------
__global__ __launch_bounds__(256) void final_mm(const float* __restrict__ ctx,
                                                const float* __restrict__ W,
                                                float* __restrict__ out)
{
  __shared__ float cs[4][1024];
  const int tid = threadIdx.x;
  const int b0 = blockIdx.x * 4;
  for(int i = tid; i < 4 * 1024; i += 256)
    cs[i >> 10][i & 1023] = ctx[(size_t)b0 * 1024 + i];
  __syncthreads();
  if(tid < 200){
    float a0 = 0, a1 = 0, a2 = 0, a3 = 0;
    for(int k = 0; k < 1024; k++){
      float wv = W[k * 200 + tid];
      a0 += cs[0][k] * wv; a1 += cs[1][k] * wv;
      a2 += cs[2][k] * wv; a3 += cs[3][k] * wv;
    }
    out[(size_t)(b0 + 0) * 200 + tid] = a0;
    out[(size_t)(b0 + 1) * 200 + tid] = a1;
    out[(size_t)(b0 + 2) * 200 + tid] = a2;
    out[(size_t)(b0 + 3) * 200 + tid] = a3;
  }
}

extern "C" void kernel_launch(void* const* d_in, const int* in_sizes, int n_in,
                              void* d_out, int out_size, void* d_ws, size_t ws_size,
                              hipStream_t stream)
{
  (void)in_sizes; (void)n_in; (void)out_size; (void)ws_size;
  const float* xl   = (const float*)d_in[0];
  const float* xr   = (const float*)d_in[1];
  const int*   lenl = (const int*)  d_in[2];
  const int*   lenr = (const int*)  d_in[3];
  const float* lW0  = (const float*)d_in[4];
  const float* lb0  = (const float*)d_in[5];
  const float* lW1  = (const float*)d_in[6];
  const float* lb1  = (const float*)d_in[7];
  const float* rW0  = (const float*)d_in[8];
  const float* rb0  = (const float*)d_in[9];
  const float* rW1  = (const float*)d_in[10];
  const float* rb1  = (const float*)d_in[11];
  const float* tW   = (const float*)d_in[12];
  float* out = (float*)d_out;
  char* ws = (char*)d_ws;

  constexpr size_t SZ_WXT0 = (size_t)2048 * Dp * 2;       // 1.31 MB
  constexpr size_t SZ_WT   = (size_t)2048 * 512 * 2;      // 2.10 MB
  constexpr size_t SZ_XPC  = (size_t)2 * MC * Dp * 2;     // 5.24 MB
  constexpr size_t SZ_ZPRE = (size_t)MC * 2048 * 2;       // 16.8 MB per side
  constexpr size_t SZ_H0   = (size_t)TC * 256 * 512 * 2;  // 4.19 MB per side
  constexpr size_t SZ_H1   = (size_t)2 * 256 * 512 * 2;   // 0.52 MB per side
  constexpr size_t SZ_CST  = (size_t)2 * 2 * 256 * 512 * 4; // 2.10 MB
  constexpr size_t SZ_CTX  = (size_t)256 * 1024 * 4;      // 1.05 MB

  size_t off = 0;
  auto carve = [&](size_t sz){ size_t o = off; off += (sz + 255) & ~(size_t)255; return o; };
  size_t o_wxt0_l = carve(SZ_WXT0), o_wxt0_r = carve(SZ_WXT0);
  size_t o_wht0_l = carve(SZ_WT),   o_wht0_r = carve(SZ_WT);
  size_t o_wxt1_l = carve(SZ_WT),   o_wxt1_r = carve(SZ_WT);
  size_t o_wht1_l = carve(SZ_WT),   o_wht1_r = carve(SZ_WT);
  size_t o_xpc    = carve(SZ_XPC);
  size_t o_zpre_l = carve(SZ_ZPRE), o_zpre_r = carve(SZ_ZPRE);
  size_t o_h0_l   = carve(SZ_H0),   o_h0_r   = carve(SZ_H0);
  size_t o_h1_l   = carve(SZ_H1),   o_h1_r   = carve(SZ_H1);
  size_t o_cst    = carve(SZ_CST);
  size_t o_ctx    = carve(SZ_CTX);
  size_t o_flags  = carve(512);   // [0..63] protocol flags, [64..] opaque sink
  // total ~67 MB

  short* wxt0_l = (short*)(ws + o_wxt0_l);
  short* wxt0_r = (short*)(ws + o_wxt0_r);
  short* wht0_l = (short*)(ws + o_wht0_l);
  short* wht0_r = (short*)(ws + o_wht0_r);
  short* wxt1_l = (short*)(ws + o_wxt1_l);
  short* wxt1_r = (short*)(ws + o_wxt1_r);
  short* wht1_l = (short*)(ws + o_wht1_l);
  short* wht1_r = (short*)(ws + o_wht1_r);
  short* xpc_l  = (short*)(ws + o_xpc);
  short* xpc_r  = xpc_l + (size_t)MC * Dp;
  short* zpre_l = (short*)(ws + o_zpre_l);
  short* zpre_r = (short*)(ws + o_zpre_r);
  short* h0_l   = (short*)(ws + o_h0_l);
  short* h0_r   = (short*)(ws + o_h0_r);
  short* h1_l   = (short*)(ws + o_h1_l);
  short* h1_r   = (short*)(ws + o_h1_r);
  float* cst    = (float*)(ws + o_cst);
  float* ctx    = (float*)(ws + o_ctx);
  unsigned* flags = (unsigned*)(ws + o_flags);

  hipMemsetAsync(flags, 0, 512, stream);

  transpose_w<<<dim3(Dp / 32, 64), 256, 0, stream>>>(lW0, wxt0_l,   0, Draw, Dp);
  transpose_w<<<dim3(Dp / 32, 64), 256, 0, stream>>>(rW0, wxt0_r,   0, Draw, Dp);
  transpose_w<<<dim3(16, 64),      256, 0, stream>>>(lW0, wht0_l, 300,  512, 512);
  transpose_w<<<dim3(16, 64),      256, 0, stream>>>(rW0, wht0_r, 300,  512, 512);
  transpose_w<<<dim3(16, 64),      256, 0, stream>>>(lW1, wxt1_l,   0,  512, 512);
  transpose_w<<<dim3(16, 64),      256, 0, stream>>>(rW1, wxt1_r,   0,  512, 512);
  transpose_w<<<dim3(16, 64),      256, 0, stream>>>(lW1, wht1_l, 512,  512, 512);
  transpose_w<<<dim3(16, 64),      256, 0, stream>>>(rW1, wht1_r, 512,  512, 512);

  for(int c = 0; c < T_ / TC; c++){
    const int t0 = c * TC;
    pad_x_chunk<<<4096, 256, 0, stream>>>(xl, xr, xpc_l, t0);
    // layer 0: Zpre = xchunk @ Wx0 + b0
    gemm_zpre<<<dim3(MC / 128, 16, 2), 256, 0, stream>>>(xpc_l, xpc_r, wxt0_l, wxt0_r,
                                                         lb0, rb0, zpre_l, zpre_r, Dp);
    lstm_rec<<<256, 256, 0, stream>>>(zpre_l, zpre_r, wht0_l, wht0_r, h0_l, h0_r,
                                      cst, nullptr, nullptr, nullptr, flags, 0, t0, 15);
    // layer 1: Zpre = h0chunk @ Wx1 + b1  (ring slot == tl for this chunk)
    gemm_zpre<<<dim3(MC / 128, 16, 2), 256, 0, stream>>>(h0_l, h0_r, wxt1_l, wxt1_r,
                                                         lb1, rb1, zpre_l, zpre_r, 512);
    lstm_rec<<<256, 256, 0, stream>>>(zpre_l, zpre_r, wht1_l, wht1_r, h1_l, h1_r,
                                      cst, lenl, lenr, ctx, flags, 1, t0, 1);
  }

  final_mm<<<64, 256, 0, stream>>>(ctx, tW, out);
}